// Round 1
// baseline (1691.853 us; speedup 1.0000x reference)
//
#include <hip/hip_runtime.h>

#define N_USERS_C 100000
#define N_NODES_C 150000
#define D 64

// One wave per edge; lane = latent dim. Coalesced gather of ego[col] row,
// coalesced atomicAdd into side[row] row.
__global__ __launch_bounds__(256) void scatter_k(
    const int* __restrict__ rows, const int* __restrict__ cols,
    const float* __restrict__ vals, const float* __restrict__ ego,
    float* __restrict__ side, int nnz)
{
    int gtid = blockIdx.x * blockDim.x + threadIdx.x;
    int wave = gtid >> 6;
    int lane = threadIdx.x & 63;
    int nwaves = (gridDim.x * blockDim.x) >> 6;
    for (int e = wave; e < nnz; e += nwaves) {
        int r = rows[e];
        int c = cols[e];
        float v = vals[e];
        atomicAdd(&side[(size_t)r * D + lane], v * ego[(size_t)c * D + lane]);
    }
}

// One wave per node row: out = l2norm(leaky_relu(side@Wg + bg + (ego*side)@Wb + bb))
// Weights staged in LDS; row operands broadcast via __shfl.
// Safe to call with out == side (row n fully read into registers before write).
__global__ __launch_bounds__(256) void transform_k(
    const float* __restrict__ ego, const float* __restrict__ side,
    const float* __restrict__ Wg, const float* __restrict__ bg,
    const float* __restrict__ Wb, const float* __restrict__ bb,
    float* __restrict__ out)
{
    __shared__ float sWg[D * D];
    __shared__ float sWb[D * D];
    for (int i = threadIdx.x; i < D * D; i += blockDim.x) {
        sWg[i] = Wg[i];
        sWb[i] = Wb[i];
    }
    __syncthreads();

    int gtid = blockIdx.x * blockDim.x + threadIdx.x;
    int wave = gtid >> 6;
    int lane = threadIdx.x & 63;
    int nwaves = (gridDim.x * blockDim.x) >> 6;

    for (int n = wave; n < N_NODES_C; n += nwaves) {
        float s = side[(size_t)n * D + lane];
        float e = ego[(size_t)n * D + lane];
        float accg = bg[lane];
        float accb = bb[lane];
        #pragma unroll 16
        for (int k = 0; k < D; ++k) {
            float sk = __shfl(s, k);
            float ek = __shfl(e, k);
            accg = fmaf(sk, sWg[k * D + lane], accg);
            accb = fmaf(ek * sk, sWb[k * D + lane], accb);
        }
        float v = accg + accb;
        v = (v > 0.0f) ? v : 0.2f * v;     // leaky_relu, slope 0.2
        float sq = v * v;
        #pragma unroll
        for (int off = 1; off < 64; off <<= 1) sq += __shfl_xor(sq, off);
        float norm = fmaxf(sqrtf(sq), 1e-12f);
        out[(size_t)n * D + lane] = v / norm;
    }
}

// One wave per batch element: gamma[b] = sum over 3 concatenated 64-d blocks.
__global__ __launch_bounds__(256) void gamma_k(
    const float* __restrict__ x, const float* __restrict__ e1,
    const float* __restrict__ e2, const int* __restrict__ users,
    const int* __restrict__ items, float* __restrict__ gamma, int batch)
{
    int gtid = blockIdx.x * blockDim.x + threadIdx.x;
    int wave = gtid >> 6;
    int lane = threadIdx.x & 63;
    if (wave >= batch) return;
    size_t u = (size_t)users[wave];
    size_t t = (size_t)(N_USERS_C + items[wave]);
    float acc = x[u * D + lane] * x[t * D + lane]
              + e1[u * D + lane] * e1[t * D + lane]
              + e2[u * D + lane] * e2[t * D + lane];
    #pragma unroll
    for (int off = 1; off < 64; off <<= 1) acc += __shfl_xor(acc, off);
    if (lane == 0) gamma[wave] = acc;
}

extern "C" void kernel_launch(void* const* d_in, const int* in_sizes, int n_in,
                              void* d_out, int out_size, void* d_ws, size_t ws_size,
                              hipStream_t stream) {
    const int*   rows  = (const int*)d_in[0];
    const int*   cols  = (const int*)d_in[1];
    const float* vals  = (const float*)d_in[2];
    const float* x     = (const float*)d_in[3];
    const int*   users = (const int*)d_in[4];
    const int*   items = (const int*)d_in[5];
    const float* Wg0 = (const float*)d_in[6];
    const float* bg0 = (const float*)d_in[7];
    const float* Wb0 = (const float*)d_in[8];
    const float* bb0 = (const float*)d_in[9];
    const float* Wg1 = (const float*)d_in[10];
    const float* bg1 = (const float*)d_in[11];
    const float* Wb1 = (const float*)d_in[12];
    const float* bb1 = (const float*)d_in[13];

    int nnz   = in_sizes[0];
    int batch = in_sizes[4];
    float* out = (float*)d_out;

    size_t emb_elems = (size_t)N_NODES_C * D;
    float* A = (float*)d_ws;            // side0 -> e1 (in place)
    float* B = A + emb_elems;           // side1 -> e2 (in place)

    // Layer 0: side = scatter(x); e1 = transform(x, side) written in place into A
    hipMemsetAsync(A, 0, emb_elems * sizeof(float), stream);
    scatter_k<<<4096, 256, 0, stream>>>(rows, cols, vals, x, A, nnz);
    transform_k<<<2048, 256, 0, stream>>>(x, A, Wg0, bg0, Wb0, bb0, A);

    // Layer 1: side = scatter(e1); e2 = transform(e1, side) in place into B
    hipMemsetAsync(B, 0, emb_elems * sizeof(float), stream);
    scatter_k<<<4096, 256, 0, stream>>>(rows, cols, vals, A, B, nnz);
    transform_k<<<2048, 256, 0, stream>>>(A, B, Wg1, bg1, Wb1, bb1, B);

    // Readout
    gamma_k<<<(batch * 64 + 255) / 256, 256, 0, stream>>>(x, A, B, users, items, out, batch);
}

// Round 2
// 1023.340 us; speedup vs baseline: 1.6533x; 1.6533x over previous
//
#include <hip/hip_runtime.h>

#define N_USERS_C 100000
#define N_NODES_C 150000
#define D 64

// ---------------- CSR build ----------------

// Histogram of row degrees.
__global__ __launch_bounds__(256) void hist_k(
    const int* __restrict__ rows, int* __restrict__ deg, int nnz)
{
    int gtid = blockIdx.x * blockDim.x + threadIdx.x;
    int stride = gridDim.x * blockDim.x;
    for (int e = gtid; e < nnz; e += stride)
        atomicAdd(&deg[rows[e]], 1);
}

// Single-block exclusive scan: rowptr[i] = sum_{j<i} deg[j], rowptr[n] = total.
// 1024 threads, tile = 1024, wave-shuffle scan + serial wave-sum scan.
__global__ __launch_bounds__(1024) void scan_k(
    const int* __restrict__ deg, int* __restrict__ rowptr, int n)
{
    __shared__ int wsum[16];
    __shared__ int woff[16];
    __shared__ int carry;
    __shared__ int tile_total;
    int lane = threadIdx.x & 63;
    int wid  = threadIdx.x >> 6;
    if (threadIdx.x == 0) carry = 0;
    __syncthreads();

    for (int base = 0; base < n; base += 1024) {
        int i = base + (int)threadIdx.x;
        int v = (i < n) ? deg[i] : 0;
        // wave-inclusive scan
        int incl = v;
        #pragma unroll
        for (int off = 1; off < 64; off <<= 1) {
            int t = __shfl_up(incl, off);
            if (lane >= off) incl += t;
        }
        if (lane == 63) wsum[wid] = incl;
        __syncthreads();
        if (threadIdx.x == 0) {
            int run = 0;
            #pragma unroll
            for (int w = 0; w < 16; ++w) { int t = wsum[w]; woff[w] = run; run += t; }
            tile_total = run;
        }
        __syncthreads();
        if (i < n) rowptr[i] = carry + woff[wid] + incl - v;  // exclusive
        __syncthreads();
        if (threadIdx.x == 0) carry += tile_total;
        // carry write is ordered vs next-tile reads by next tile's first sync
    }
    __syncthreads();
    if (threadIdx.x == 0) rowptr[n] = carry;
}

// Reorder edges into CSR slot order: pairs[p] = (col, val_bits).
__global__ __launch_bounds__(256) void fill_k(
    const int* __restrict__ rows, const int* __restrict__ cols,
    const float* __restrict__ vals, int* __restrict__ cursor,
    int2* __restrict__ pairs, int nnz)
{
    int gtid = blockIdx.x * blockDim.x + threadIdx.x;
    int stride = gridDim.x * blockDim.x;
    for (int e = gtid; e < nnz; e += stride) {
        int r = rows[e];
        int p = atomicAdd(&cursor[r], 1);
        pairs[p] = make_int2(cols[e], __float_as_int(vals[e]));
    }
}

// ---------------- Fused gather + transform ----------------
// One wave per output row n: side = sum_{edges of n} val * ego[col] accumulated
// in registers (lane = dim), then out[n] = l2norm(leaky_relu(side@Wg + bg +
// (ego[n]*side)@Wb + bb)). If `u` is non-null, rows come from the sampled
// node list (users then N_USERS+items) — layer-2 mode.
__global__ __launch_bounds__(256) void gt_k(
    const int* __restrict__ rowptr, const int2* __restrict__ pairs,
    const float* __restrict__ ego,
    const float* __restrict__ Wg, const float* __restrict__ bg,
    const float* __restrict__ Wb, const float* __restrict__ bb,
    float* __restrict__ out,
    const int* __restrict__ u, const int* __restrict__ it,
    int nrows, int batch)
{
    __shared__ float sWg[D * D];
    __shared__ float sWb[D * D];
    __shared__ float sbg[D];
    __shared__ float sbb[D];
    for (int i = threadIdx.x; i < D * D; i += blockDim.x) {
        sWg[i] = Wg[i];
        sWb[i] = Wb[i];
    }
    if (threadIdx.x < D) { sbg[threadIdx.x] = bg[threadIdx.x]; sbb[threadIdx.x] = bb[threadIdx.x]; }
    __syncthreads();

    int gtid = blockIdx.x * blockDim.x + threadIdx.x;
    int wave = gtid >> 6;
    int lane = threadIdx.x & 63;
    int nwaves = (gridDim.x * blockDim.x) >> 6;

    for (int r = wave; r < nrows; r += nwaves) {
        int n = u ? ((r < batch) ? u[r] : N_USERS_C + it[r - batch]) : r;
        int s = rowptr[n];
        int epd = rowptr[n + 1];

        float acc = 0.0f;
        for (int base = s; base < epd; base += 64) {
            int2 p = make_int2(0, 0);
            if (base + lane < epd) p = pairs[base + lane];
            int cnt = min(epd - base, 64);
            for (int j = 0; j < cnt; ++j) {
                int   cj = __shfl(p.x, j);
                float vj = __int_as_float(__shfl(p.y, j));
                acc = fmaf(vj, ego[(size_t)cj * D + lane], acc);
            }
        }

        float e = ego[(size_t)n * D + lane];
        float accg = sbg[lane];
        float accb = sbb[lane];
        #pragma unroll 16
        for (int k = 0; k < D; ++k) {
            float sk = __shfl(acc, k);
            float ek = __shfl(e, k);
            accg = fmaf(sk, sWg[k * D + lane], accg);
            accb = fmaf(ek * sk, sWb[k * D + lane], accb);
        }
        float v = accg + accb;
        v = (v > 0.0f) ? v : 0.2f * v;        // leaky_relu slope 0.2
        float sq = v * v;
        #pragma unroll
        for (int off = 1; off < 64; off <<= 1) sq += __shfl_xor(sq, off);
        float norm = fmaxf(sqrtf(sq), 1e-12f);
        out[(size_t)n * D + lane] = v / norm;
    }
}

// One wave per batch element: gamma[b] = <concat(x,e1,e2)[u], concat(x,e1,e2)[i]>.
__global__ __launch_bounds__(256) void gamma_k(
    const float* __restrict__ x, const float* __restrict__ e1,
    const float* __restrict__ e2, const int* __restrict__ users,
    const int* __restrict__ items, float* __restrict__ gamma, int batch)
{
    int gtid = blockIdx.x * blockDim.x + threadIdx.x;
    int wave = gtid >> 6;
    int lane = threadIdx.x & 63;
    if (wave >= batch) return;
    size_t uu = (size_t)users[wave];
    size_t tt = (size_t)(N_USERS_C + items[wave]);
    float acc = x[uu * D + lane] * x[tt * D + lane]
              + e1[uu * D + lane] * e1[tt * D + lane]
              + e2[uu * D + lane] * e2[tt * D + lane];
    #pragma unroll
    for (int off = 1; off < 64; off <<= 1) acc += __shfl_xor(acc, off);
    if (lane == 0) gamma[wave] = acc;
}

extern "C" void kernel_launch(void* const* d_in, const int* in_sizes, int n_in,
                              void* d_out, int out_size, void* d_ws, size_t ws_size,
                              hipStream_t stream) {
    const int*   rows  = (const int*)d_in[0];
    const int*   cols  = (const int*)d_in[1];
    const float* vals  = (const float*)d_in[2];
    const float* x     = (const float*)d_in[3];
    const int*   users = (const int*)d_in[4];
    const int*   items = (const int*)d_in[5];
    const float* Wg0 = (const float*)d_in[6];
    const float* bg0 = (const float*)d_in[7];
    const float* Wb0 = (const float*)d_in[8];
    const float* bb0 = (const float*)d_in[9];
    const float* Wg1 = (const float*)d_in[10];
    const float* bg1 = (const float*)d_in[11];
    const float* Wb1 = (const float*)d_in[12];
    const float* bb1 = (const float*)d_in[13];

    int nnz   = in_sizes[0];
    int batch = in_sizes[4];
    float* out = (float*)d_out;

    size_t emb_elems = (size_t)N_NODES_C * D;
    float* A = (float*)d_ws;                 // e1 (all nodes)
    float* B = A + emb_elems;                // e2 (sampled rows only)
    int*   rowptr = (int*)(B + emb_elems);   // 150002 (padded to even)
    int*   cursor = rowptr + (N_NODES_C + 2);
    int*   deg    = cursor + N_NODES_C;
    int2*  pairs  = (int2*)(deg + N_NODES_C);

    // --- CSR build (shared by both layers) ---
    hipMemsetAsync(deg, 0, N_NODES_C * sizeof(int), stream);
    hist_k<<<2048, 256, 0, stream>>>(rows, deg, nnz);
    scan_k<<<1, 1024, 0, stream>>>(deg, rowptr, N_NODES_C);
    hipMemcpyAsync(cursor, rowptr, N_NODES_C * sizeof(int),
                   hipMemcpyDeviceToDevice, stream);
    fill_k<<<2048, 256, 0, stream>>>(rows, cols, vals, cursor, pairs, nnz);

    // --- Layer 1: all nodes ---
    gt_k<<<(N_NODES_C + 3) / 4, 256, 0, stream>>>(
        rowptr, pairs, x, Wg0, bg0, Wb0, bb0, A,
        nullptr, nullptr, N_NODES_C, 0);

    // --- Layer 2: only the 2*batch sampled nodes are consumed by gamma ---
    gt_k<<<(2 * batch + 3) / 4, 256, 0, stream>>>(
        rowptr, pairs, A, Wg1, bg1, Wb1, bb1, B,
        users, items, 2 * batch, batch);

    // --- Readout ---
    gamma_k<<<(batch * 64 + 255) / 256, 256, 0, stream>>>(
        x, A, B, users, items, out, batch);
}

// Round 3
// 485.700 us; speedup vs baseline: 3.4833x; 2.1069x over previous
//
#include <hip/hip_runtime.h>

#define N_USERS_C 100000
#define N_NODES_C 150000
#define D 64
#define SPAD 68   // transposed-tile row stride (floats); 272B = 16B-aligned

// ---------------- CSR build ----------------

__global__ __launch_bounds__(256) void hist_k(
    const int* __restrict__ rows, int* __restrict__ deg, int nnz)
{
    int gtid = blockIdx.x * blockDim.x + threadIdx.x;
    int stride = gridDim.x * blockDim.x;
    for (int e = gtid; e < nnz; e += stride)
        atomicAdd(&deg[rows[e]], 1);
}

// Per-block (1024) exclusive scan; partial result into part, block sum into bsum.
__global__ __launch_bounds__(1024) void scan1_k(
    const int* __restrict__ deg, int* __restrict__ part, int* __restrict__ bsum, int n)
{
    __shared__ int wsum[16];
    int i = blockIdx.x * 1024 + threadIdx.x;
    int lane = threadIdx.x & 63, wid = threadIdx.x >> 6;
    int v = (i < n) ? deg[i] : 0;
    int incl = v;
    #pragma unroll
    for (int off = 1; off < 64; off <<= 1) {
        int t = __shfl_up(incl, off);
        if (lane >= off) incl += t;
    }
    if (lane == 63) wsum[wid] = incl;
    __syncthreads();
    int woff = 0;
    for (int w = 0; w < wid; ++w) woff += wsum[w];
    if (i < n) part[i] = woff + incl - v;
    if (threadIdx.x == 1023) bsum[blockIdx.x] = woff + incl;
}

// Exclusive scan of block sums in place (nb <= 1024), one block.
__global__ __launch_bounds__(1024) void scan2_k(int* __restrict__ bsum, int nb)
{
    __shared__ int wsum[16];
    int lane = threadIdx.x & 63, wid = threadIdx.x >> 6;
    int i = threadIdx.x;
    int v = (i < nb) ? bsum[i] : 0;
    int incl = v;
    #pragma unroll
    for (int off = 1; off < 64; off <<= 1) {
        int t = __shfl_up(incl, off);
        if (lane >= off) incl += t;
    }
    if (lane == 63) wsum[wid] = incl;
    __syncthreads();
    int woff = 0;
    for (int w = 0; w < wid; ++w) woff += wsum[w];
    if (i < nb) bsum[i] = woff + incl - v;
}

// Add block offsets; write final rowptr and cursor copy.
__global__ __launch_bounds__(256) void scan3_k(
    const int* __restrict__ bsum, int* __restrict__ rowptr,
    int* __restrict__ cursor, int n, int nnz)
{
    int i = blockIdx.x * blockDim.x + threadIdx.x;
    if (i < n) {
        int val = rowptr[i] + bsum[i >> 10];
        rowptr[i] = val;
        cursor[i] = val;
    }
    if (i == 0) rowptr[n] = nnz;
}

__global__ __launch_bounds__(256) void fill_k(
    const int* __restrict__ rows, const int* __restrict__ cols,
    const float* __restrict__ vals, int* __restrict__ cursor,
    int2* __restrict__ pairs, int nnz)
{
    int gtid = blockIdx.x * blockDim.x + threadIdx.x;
    int stride = gridDim.x * blockDim.x;
    for (int e = gtid; e < nnz; e += stride) {
        int r = rows[e];
        int p = atomicAdd(&cursor[r], 1);
        pairs[p] = make_int2(cols[e], __float_as_int(vals[e]));
    }
}

// ---------------- CSR gather (segment-sum) ----------------
// One wave per output row; lane = dim. 4-wide unrolled edge loop (zero-padded)
// gives 4 independent row-gathers in flight. No LDS -> full occupancy.
// If u != null: sampled mode (row r -> node users[r] / N_USERS+items[r-batch]),
// and also copies ego[n] row into egoc[r] (needed by the bi-term downstream).
__global__ __launch_bounds__(256) void gather_k(
    const int* __restrict__ rowptr, const int2* __restrict__ pairs,
    const float* __restrict__ ego, float* __restrict__ side,
    float* __restrict__ egoc,
    const int* __restrict__ u, const int* __restrict__ it,
    int nrows, int batch)
{
    int gtid = blockIdx.x * blockDim.x + threadIdx.x;
    int wave = gtid >> 6;
    int lane = threadIdx.x & 63;
    if (wave >= nrows) return;
    int r = wave;
    int n = u ? ((r < batch) ? u[r] : N_USERS_C + it[r - batch]) : r;
    int s  = rowptr[n];
    int ep = rowptr[n + 1];

    float acc = 0.0f;
    for (int base = s; base < ep; base += 64) {
        int2 p = make_int2(0, 0);
        if (base + lane < ep) p = pairs[base + lane];
        int cnt4 = (min(ep - base, 64) + 3) & ~3;
        for (int j = 0; j < cnt4; j += 4) {
            int c0 = __shfl(p.x, j + 0);
            int c1 = __shfl(p.x, j + 1);
            int c2 = __shfl(p.x, j + 2);
            int c3 = __shfl(p.x, j + 3);
            float v0 = __int_as_float(__shfl(p.y, j + 0));
            float v1 = __int_as_float(__shfl(p.y, j + 1));
            float v2 = __int_as_float(__shfl(p.y, j + 2));
            float v3 = __int_as_float(__shfl(p.y, j + 3));
            float f0 = ego[(size_t)c0 * D + lane];
            float f1 = ego[(size_t)c1 * D + lane];
            float f2 = ego[(size_t)c2 * D + lane];
            float f3 = ego[(size_t)c3 * D + lane];
            acc = fmaf(v0, f0, acc);
            acc = fmaf(v1, f1, acc);
            acc = fmaf(v2, f2, acc);
            acc = fmaf(v3, f3, acc);
        }
    }
    side[(size_t)r * D + lane] = acc;
    if (egoc) egoc[(size_t)r * D + lane] = ego[(size_t)n * D + lane];
}

// ---------------- Tiled transform: out = l2norm(leaky(S@Wg + (E*S)@Wb + bg+bb)) ----------------
// 64-row tile per block, 256 threads as 16(tr: 4 rows each) x 16(tc: 4 cols each),
// 4x4 register accumulators, float4 LDS reads from transposed tiles.
__global__ __launch_bounds__(256) void transform_k(
    const float* __restrict__ S, const float* __restrict__ E,
    const float* __restrict__ Wg, const float* __restrict__ bg,
    const float* __restrict__ Wb, const float* __restrict__ bb,
    float* __restrict__ out, int nrows)
{
    __shared__ __align__(16) float sWg[D * D];
    __shared__ __align__(16) float sWb[D * D];
    __shared__ __align__(16) float sAT[D][SPAD];   // side, transposed: [k][row]
    __shared__ __align__(16) float sBT[D][SPAD];   // ego*side, transposed

    int t  = threadIdx.x;
    int tc = t & 15;
    int tr = t >> 4;
    int r0 = blockIdx.x * 64;

    for (int i = t; i < D * D; i += 256) {
        sWg[i] = Wg[i];
        sWb[i] = Wb[i];
    }
    // stage tiles transposed: 4 passes x 16 rows; each thread one float4 of S/E
    for (int itr = 0; itr < 4; ++itr) {
        int rr  = itr * 16 + (t >> 4);
        int row = r0 + rr;
        float4 sv = make_float4(0.f, 0.f, 0.f, 0.f);
        float4 ev = sv;
        if (row < nrows) {
            sv = *(const float4*)&S[(size_t)row * D + tc * 4];
            ev = *(const float4*)&E[(size_t)row * D + tc * 4];
        }
        sAT[tc * 4 + 0][rr] = sv.x;
        sAT[tc * 4 + 1][rr] = sv.y;
        sAT[tc * 4 + 2][rr] = sv.z;
        sAT[tc * 4 + 3][rr] = sv.w;
        sBT[tc * 4 + 0][rr] = sv.x * ev.x;
        sBT[tc * 4 + 1][rr] = sv.y * ev.y;
        sBT[tc * 4 + 2][rr] = sv.z * ev.z;
        sBT[tc * 4 + 3][rr] = sv.w * ev.w;
    }
    __syncthreads();

    float acc[4][4] = {};
    for (int k = 0; k < D; ++k) {
        float4 a4 = *(const float4*)&sAT[k][tr * 4];
        float4 b4 = *(const float4*)&sBT[k][tr * 4];
        float4 g4 = *(const float4*)&sWg[k * D + tc * 4];
        float4 w4 = *(const float4*)&sWb[k * D + tc * 4];
        float av[4] = {a4.x, a4.y, a4.z, a4.w};
        float bv[4] = {b4.x, b4.y, b4.z, b4.w};
        float gv[4] = {g4.x, g4.y, g4.z, g4.w};
        float wv[4] = {w4.x, w4.y, w4.z, w4.w};
        #pragma unroll
        for (int i = 0; i < 4; ++i)
            #pragma unroll
            for (int j = 0; j < 4; ++j)
                acc[i][j] = fmaf(av[i], gv[j], fmaf(bv[i], wv[j], acc[i][j]));
    }

    float4 bgv = *(const float4*)&bg[tc * 4];
    float4 bbv = *(const float4*)&bb[tc * 4];
    float bias[4] = {bgv.x + bbv.x, bgv.y + bbv.y, bgv.z + bbv.z, bgv.w + bbv.w};

    float vv[4][4];
    float ss[4] = {0.f, 0.f, 0.f, 0.f};
    #pragma unroll
    for (int i = 0; i < 4; ++i) {
        #pragma unroll
        for (int j = 0; j < 4; ++j) {
            float v = acc[i][j] + bias[j];
            v = (v > 0.0f) ? v : 0.2f * v;   // leaky_relu slope 0.2
            vv[i][j] = v;
            ss[i] += v * v;
        }
    }
    // reduce sum-of-squares across the 16 tc-lanes (consecutive within wave)
    #pragma unroll
    for (int i = 0; i < 4; ++i) {
        #pragma unroll
        for (int off = 1; off < 16; off <<= 1)
            ss[i] += __shfl_xor(ss[i], off);
    }
    #pragma unroll
    for (int i = 0; i < 4; ++i) {
        int row = r0 + tr * 4 + i;
        if (row < nrows) {
            float inv = 1.0f / fmaxf(sqrtf(ss[i]), 1e-12f);
            float4 o = make_float4(vv[i][0] * inv, vv[i][1] * inv,
                                   vv[i][2] * inv, vv[i][3] * inv);
            *(float4*)&out[(size_t)row * D + tc * 4] = o;
        }
    }
}

// ---------------- Readout ----------------
// gamma[b] = <x[u],x[i]> + <e1[u],e1[i]> + <e2c[b],e2c[batch+b]>
__global__ __launch_bounds__(256) void gamma_k(
    const float* __restrict__ x, const float* __restrict__ e1,
    const float* __restrict__ e2c, const int* __restrict__ users,
    const int* __restrict__ items, float* __restrict__ gamma, int batch)
{
    int gtid = blockIdx.x * blockDim.x + threadIdx.x;
    int wave = gtid >> 6;
    int lane = threadIdx.x & 63;
    if (wave >= batch) return;
    size_t uu = (size_t)users[wave];
    size_t tt = (size_t)(N_USERS_C + items[wave]);
    float acc = x[uu * D + lane] * x[tt * D + lane]
              + e1[uu * D + lane] * e1[tt * D + lane]
              + e2c[(size_t)wave * D + lane] * e2c[(size_t)(batch + wave) * D + lane];
    #pragma unroll
    for (int off = 1; off < 64; off <<= 1) acc += __shfl_xor(acc, off);
    if (lane == 0) gamma[wave] = acc;
}

extern "C" void kernel_launch(void* const* d_in, const int* in_sizes, int n_in,
                              void* d_out, int out_size, void* d_ws, size_t ws_size,
                              hipStream_t stream) {
    const int*   rows  = (const int*)d_in[0];
    const int*   cols  = (const int*)d_in[1];
    const float* vals  = (const float*)d_in[2];
    const float* x     = (const float*)d_in[3];
    const int*   users = (const int*)d_in[4];
    const int*   items = (const int*)d_in[5];
    const float* Wg0 = (const float*)d_in[6];
    const float* bg0 = (const float*)d_in[7];
    const float* Wb0 = (const float*)d_in[8];
    const float* bb0 = (const float*)d_in[9];
    const float* Wg1 = (const float*)d_in[10];
    const float* bg1 = (const float*)d_in[11];
    const float* Wb1 = (const float*)d_in[12];
    const float* bb1 = (const float*)d_in[13];

    int nnz   = in_sizes[0];
    int batch = in_sizes[4];
    float* out = (float*)d_out;

    size_t emb = (size_t)N_NODES_C * D;
    float* A      = (float*)d_ws;           // e1 [150k x 64]
    float* Sbuf   = A + emb;                // side (L1); reused for compacts after
    int*   rowptr = (int*)(Sbuf + emb);     // N+1 (padded)
    int*   cursor = rowptr + (N_NODES_C + 16);
    int*   deg    = cursor + (N_NODES_C + 16);
    int*   bsum   = deg + (N_NODES_C + 16);  // 256
    int2*  pairs  = (int2*)(bsum + 256);     // nnz

    // compact layer-2 buffers live in Sbuf (free after transform1)
    float* side2c = Sbuf;                    // [2B x 64]
    float* egoc   = Sbuf + (size_t)2 * 2048 * D;
    float* e2c    = egoc + (size_t)2 * 2048 * D;

    int nscan = (N_NODES_C + 1023) / 1024;   // 147

    // --- CSR build ---
    hipMemsetAsync(deg, 0, N_NODES_C * sizeof(int), stream);
    hist_k<<<1024, 256, 0, stream>>>(rows, deg, nnz);
    scan1_k<<<nscan, 1024, 0, stream>>>(deg, rowptr, bsum, N_NODES_C);
    scan2_k<<<1, 1024, 0, stream>>>(bsum, nscan);
    scan3_k<<<(N_NODES_C + 255) / 256, 256, 0, stream>>>(bsum, rowptr, cursor, N_NODES_C, nnz);
    fill_k<<<1024, 256, 0, stream>>>(rows, cols, vals, cursor, pairs, nnz);

    // --- Layer 1 (all nodes): side = A_hat @ x ; e1 = transform ---
    gather_k<<<(N_NODES_C * 64 + 255) / 256, 256, 0, stream>>>(
        rowptr, pairs, x, Sbuf, nullptr, nullptr, nullptr, N_NODES_C, 0);
    transform_k<<<(N_NODES_C + 63) / 64, 256, 0, stream>>>(
        Sbuf, x, Wg0, bg0, Wb0, bb0, A, N_NODES_C);

    // --- Layer 2 (sampled 2*batch rows, compact) ---
    gather_k<<<(2 * batch * 64 + 255) / 256, 256, 0, stream>>>(
        rowptr, pairs, A, side2c, egoc, users, items, 2 * batch, batch);
    transform_k<<<(2 * batch + 63) / 64, 256, 0, stream>>>(
        side2c, egoc, Wg1, bg1, Wb1, bb1, e2c, 2 * batch);

    // --- Readout ---
    gamma_k<<<(batch * 64 + 255) / 256, 256, 0, stream>>>(
        x, A, e2c, users, items, out, batch);
}